// Round 2
// baseline (517.039 us; speedup 1.0000x reference)
//
#include <hip/hip_runtime.h>

typedef unsigned short u16;
typedef unsigned int u32;
typedef __bf16 bf16x8 __attribute__((ext_vector_type(8)));
typedef float f32x4 __attribute__((ext_vector_type(4)));

// workspace offsets in u16 elements
#define WT_HI_E  ((size_t)0)             // 3 x 1M
#define WT_LO_E  ((size_t)3 << 20)
#define X_HI_E   ((size_t)6 << 20)       // 4M each below
#define X_LO_E   ((size_t)10 << 20)
#define Q_HI_E   ((size_t)14 << 20)
#define Q_LO_E   ((size_t)18 << 20)
#define K_HI_E   ((size_t)22 << 20)
#define K_LO_E   ((size_t)26 << 20)
#define V_HI_E   ((size_t)30 << 20)      // V^T layout [hb][d][s]; ends at 34M u16 = 68 MB
// attention partials reuse the dead WT/X region after k_proj:
//   o1 (split-1 partial O, fp32)  : u16 [0, 8M)    = 32*2048*64 floats
//   m0,l0,m1,l1 (fp32, 65536 each): u16 [8M, 8.5M)
#define O1_E     ((size_t)0)
#define ML_E     ((size_t)8 << 20)

__device__ __forceinline__ u16 bf16_rne(float x) {
  u32 u = __float_as_uint(x);
  u32 r = (u + 0x7fffu + ((u >> 16) & 1u)) >> 16;
  return (u16)r;
}
__device__ __forceinline__ float bf16_f(u16 h) {
  return __uint_as_float(((u32)h) << 16);
}

__device__ __forceinline__ void gload16(const u16* g, u16* l) {
  __builtin_amdgcn_global_load_lds(
      (const __attribute__((address_space(1))) void*)g,
      (__attribute__((address_space(3))) void*)l, 16, 0, 0);
}

// ---------------- X split: fp32 -> bf16 hi/lo ----------------
__global__ __launch_bounds__(256) void k_xsplit(const float* __restrict__ X,
                                                u16* __restrict__ ws) {
  u16* xh = ws + X_HI_E;
  u16* xl = ws + X_LO_E;
  size_t i = ((size_t)blockIdx.x * 256 + threadIdx.x) * 8;
  float4 a = *(const float4*)(X + i);
  float4 b = *(const float4*)(X + i + 4);
  float v[8] = {a.x, a.y, a.z, a.w, b.x, b.y, b.z, b.w};
  u32 Hh[4], Ll[4];
#pragma unroll
  for (int j = 0; j < 4; j++) {
    u16 h0 = bf16_rne(v[2 * j]);
    u16 l0 = bf16_rne(v[2 * j] - bf16_f(h0));
    u16 h1 = bf16_rne(v[2 * j + 1]);
    u16 l1 = bf16_rne(v[2 * j + 1] - bf16_f(h1));
    Hh[j] = (u32)h0 | ((u32)h1 << 16);
    Ll[j] = (u32)l0 | ((u32)l1 << 16);
  }
  *(uint4*)(xh + i) = make_uint4(Hh[0], Hh[1], Hh[2], Hh[3]);
  *(uint4*)(xl + i) = make_uint4(Ll[0], Ll[1], Ll[2], Ll[3]);
}

// ---------------- W transpose + split: W[k][n] -> Wt_hi/lo[n][k] ----------------
__global__ __launch_bounds__(256) void k_wsplit(const float* __restrict__ w0,
                                                const float* __restrict__ w1,
                                                const float* __restrict__ w2,
                                                u16* __restrict__ ws) {
  int z = blockIdx.z;
  const float* W = (z == 0) ? w0 : ((z == 1) ? w1 : w2);
  u16* th = ws + WT_HI_E + (size_t)z * (1u << 20);
  u16* tl = ws + WT_LO_E + (size_t)z * (1u << 20);
  __shared__ float tile[32][33];
  int bx = blockIdx.x * 32, by = blockIdx.y * 32;
  int tx = threadIdx.x & 31, ty = threadIdx.x >> 5;  // 32 x 8
#pragma unroll
  for (int i = 0; i < 4; i++) {
    int r = ty + i * 8;
    tile[r][tx] = W[(size_t)(by + r) * 1024 + bx + tx];
  }
  __syncthreads();
#pragma unroll
  for (int i = 0; i < 4; i++) {
    int r = ty + i * 8;
    float v = tile[tx][r];  // = W[by+tx][bx+r]
    int n = bx + r, k = by + tx;
    u16 h = bf16_rne(v);
    u16 l = bf16_rne(v - bf16_f(h));
    th[(size_t)n * 1024 + k] = h;
    tl[(size_t)n * 1024 + k] = l;
  }
}

// ---------------- projections: Y = X @ W, compensated bf16 MFMA ----------------
// z=0 -> Q*0.125 (hi+lo), z=1 -> K (hi+lo), z=2 -> V (hi only, stored transposed).
// Q/K layout [h*2+b][s][d]; V layout [h*2+b][d][s].
__global__ __launch_bounds__(256) void k_proj(u16* __restrict__ ws) {
  int z = blockIdx.z;
  const u16* Xh = ws + X_HI_E;
  const u16* Xl = ws + X_LO_E;
  const u16* Wh = ws + WT_HI_E + (size_t)z * (1u << 20);
  const u16* Wl = ws + WT_LO_E + (size_t)z * (1u << 20);
  u16* dsth = ws + ((z == 0) ? Q_HI_E : ((z == 1) ? K_HI_E : V_HI_E));
  u16* dstl = (z == 0) ? (ws + Q_LO_E) : ((z == 1) ? (ws + K_LO_E) : (u16*)0);

  // unpadded (global_load_lds requires lane-contiguous LDS) — frag reads are
  // conflict-optimal for [128][32] u16 (8 lanes/bank-slot uniform).
  __shared__ u16 sXh[4096], sXl[4096], sWh[4096], sWl[4096];
  int M0 = blockIdx.y * 128, N0 = blockIdx.x * 128;
  int tid = threadIdx.x, lane = tid & 63, w = tid >> 6;
  int quad = lane >> 4, l16 = lane & 15;
  int mb = (w & 1) * 64, nb = (w >> 1) * 64;

  const f32x4 z4 = {0.f, 0.f, 0.f, 0.f};
  f32x4 acc[4][4];
#pragma unroll
  for (int i = 0; i < 4; i++)
#pragma unroll
    for (int j = 0; j < 4; j++) acc[i][j] = z4;

  for (int kk = 0; kk < 1024; kk += 32) {
    __syncthreads();
#pragma unroll
    for (int c2 = 0; c2 < 2; c2++) {
      int cb = c2 * 256 + w * 64;
      int c = cb + lane;
      int row = c >> 2, q8 = c & 3;
      size_t gx = (size_t)(M0 + row) * 1024 + kk + q8 * 8;
      size_t gw = (size_t)(N0 + row) * 1024 + kk + q8 * 8;
      gload16(Xh + gx, sXh + (size_t)cb * 8);
      gload16(Wh + gw, sWh + (size_t)cb * 8);
      if (z != 2) {
        gload16(Xl + gx, sXl + (size_t)cb * 8);
        gload16(Wl + gw, sWl + (size_t)cb * 8);
      }
    }
    __syncthreads();
    bf16x8 ah[4], bh[4];
#pragma unroll
    for (int i = 0; i < 4; i++) {
      ah[i] = *(const bf16x8*)&sXh[(mb + i * 16 + l16) * 32 + quad * 8];
      bh[i] = *(const bf16x8*)&sWh[(nb + i * 16 + l16) * 32 + quad * 8];
    }
    if (z != 2) {
      bf16x8 al[4], bl[4];
#pragma unroll
      for (int i = 0; i < 4; i++) {
        al[i] = *(const bf16x8*)&sXl[(mb + i * 16 + l16) * 32 + quad * 8];
        bl[i] = *(const bf16x8*)&sWl[(nb + i * 16 + l16) * 32 + quad * 8];
      }
#pragma unroll
      for (int i = 0; i < 4; i++)
#pragma unroll
        for (int j = 0; j < 4; j++) {
          f32x4 c0 = acc[i][j];
          c0 = __builtin_amdgcn_mfma_f32_16x16x32_bf16(ah[i], bh[j], c0, 0, 0, 0);
          c0 = __builtin_amdgcn_mfma_f32_16x16x32_bf16(ah[i], bl[j], c0, 0, 0, 0);
          c0 = __builtin_amdgcn_mfma_f32_16x16x32_bf16(al[i], bh[j], c0, 0, 0, 0);
          acc[i][j] = c0;
        }
    } else {
#pragma unroll
      for (int i = 0; i < 4; i++)
#pragma unroll
        for (int j = 0; j < 4; j++)
          acc[i][j] = __builtin_amdgcn_mfma_f32_16x16x32_bf16(ah[i], bh[j], acc[i][j], 0, 0, 0);
    }
  }

  if (z == 2) {
    // V^T: per (i,j) the 4 r-values are 4 consecutive s at fixed d -> one b64 store
#pragma unroll
    for (int i = 0; i < 4; i++)
#pragma unroll
      for (int j = 0; j < 4; j++) {
        int mg = M0 + mb + i * 16 + quad * 4;
        int ng = N0 + nb + j * 16 + l16;
        int b = mg >> 11, s = mg & 2047;
        int hh = ng >> 6, d = ng & 63;
        u16 p0 = bf16_rne(acc[i][j][0]);
        u16 p1 = bf16_rne(acc[i][j][1]);
        u16 p2 = bf16_rne(acc[i][j][2]);
        u16 p3 = bf16_rne(acc[i][j][3]);
        *(uint2*)&dsth[((size_t)(hh * 2 + b) * 64 + d) * 2048 + s] =
            make_uint2((u32)p0 | ((u32)p1 << 16), (u32)p2 | ((u32)p3 << 16));
      }
  } else {
    float qscale = (z == 0) ? 0.125f : 1.0f;  // fold 1/sqrt(dh) into Q (exact pow2)
#pragma unroll
    for (int i = 0; i < 4; i++)
#pragma unroll
      for (int j = 0; j < 4; j++)
#pragma unroll
        for (int r = 0; r < 4; r++) {
          int mg = M0 + mb + i * 16 + quad * 4 + r;
          int ng = N0 + nb + j * 16 + l16;
          int b = mg >> 11, s = mg & 2047;
          int hh = ng >> 6, d = ng & 63;
          size_t idx = ((size_t)(hh * 2 + b) * 2048 + s) * 64 + d;
          float y = acc[i][j][r] * qscale;
          u16 h = bf16_rne(y);
          dsth[idx] = h;
          dstl[idx] = bf16_rne(y - bf16_f(h));
        }
  }
}

// ---------------- flash attention, barrier-free, kt-split x2 ----------------
// grid 2048 (1D, XCD-swizzled), 4 waves/block, 16 Q-rows/wave (BQ=64).
// K and V^T fragments loaded directly from global (L1-shared across waves).
// Writes UNNORMALIZED partial O + (m,l); k_combine merges the 2 kt-splits.
__global__ __launch_bounds__(256, 4) void k_attn(u16* __restrict__ ws,
                                                 float* __restrict__ out) {
  const u16* Qh = ws + Q_HI_E;
  const u16* Ql = ws + Q_LO_E;
  const u16* Kh = ws + K_HI_E;
  const u16* Kl = ws + K_LO_E;
  const u16* Vt = ws + V_HI_E;
  float* o1 = (float*)(ws + O1_E);
  float* ml = (float*)(ws + ML_E);  // m0,l0,m1,l1 each 65536 floats

  __shared__ u16 sP[4][16][68];  // wave-private; pad 68: writes 2-way (free), reads optimal

  // XCD swizzle: consecutive blocks (round-robin over 8 XCDs) share hb
  int id = blockIdx.x;
  int xcd = id & 7, j = id >> 3;
  int hb = xcd + 8 * (j >> 6);
  int rem = j & 63;
  int qb = rem >> 1, split = rem & 1;
  int q0 = qb * 64;
  int kt0 = split * 1024;

  int tid = threadIdx.x, w = tid >> 6, lane = tid & 63;
  int quad = lane >> 4, l16 = lane & 15;
  size_t base = (size_t)hb * (2048 * 64);
  int row0 = q0 + w * 16;

  bf16x8 qh[2], ql[2];
#pragma unroll
  for (int kc = 0; kc < 2; kc++) {
    size_t off = base + (size_t)(row0 + l16) * 64 + kc * 32 + quad * 8;
    qh[kc] = *(const bf16x8*)(Qh + off);
    ql[kc] = *(const bf16x8*)(Ql + off);
  }
  const f32x4 z4 = {0.f, 0.f, 0.f, 0.f};
  float mr[4], lr[4];
  f32x4 o[4];
#pragma unroll
  for (int dn = 0; dn < 4; dn++) o[dn] = z4;
#pragma unroll
  for (int r = 0; r < 4; r++) {
    mr[r] = -1e30f;
    lr[r] = 0.f;
  }

  for (int it = 0; it < 16; it++) {
    int kt = kt0 + it * 64;
    f32x4 sc[4] = {z4, z4, z4, z4};
#pragma unroll
    for (int kc = 0; kc < 2; kc++) {
      bf16x8 kh[4], klo[4];
#pragma unroll
      for (int nt = 0; nt < 4; nt++) {
        size_t ko = base + (size_t)(kt + nt * 16 + l16) * 64 + kc * 32 + quad * 8;
        kh[nt] = *(const bf16x8*)(Kh + ko);
        klo[nt] = *(const bf16x8*)(Kl + ko);
      }
#pragma unroll
      for (int nt = 0; nt < 4; nt++) {
        f32x4 a = sc[nt];
        a = __builtin_amdgcn_mfma_f32_16x16x32_bf16(qh[kc], kh[nt], a, 0, 0, 0);
        a = __builtin_amdgcn_mfma_f32_16x16x32_bf16(qh[kc], klo[nt], a, 0, 0, 0);
        a = __builtin_amdgcn_mfma_f32_16x16x32_bf16(ql[kc], kh[nt], a, 0, 0, 0);
        sc[nt] = a;
      }
    }
    // online softmax; scale already folded into Q
#pragma unroll
    for (int r = 0; r < 4; r++) {
      float m1v = fmaxf(fmaxf(sc[0][r], sc[1][r]), fmaxf(sc[2][r], sc[3][r]));
#pragma unroll
      for (int off = 1; off < 16; off <<= 1) m1v = fmaxf(m1v, __shfl_xor(m1v, off));
      float mnew = fmaxf(mr[r], m1v);
      float alpha = __expf(mr[r] - mnew);
      mr[r] = mnew;
      float rs = 0.f;
#pragma unroll
      for (int nt = 0; nt < 4; nt++) {
        float p = __expf(sc[nt][r] - mnew);
        rs += p;
        sP[w][quad * 4 + r][nt * 16 + l16] = bf16_rne(p);
      }
#pragma unroll
      for (int off = 1; off < 16; off <<= 1) rs += __shfl_xor(rs, off);
      lr[r] = lr[r] * alpha + rs;
#pragma unroll
      for (int dn = 0; dn < 4; dn++) o[dn][r] *= alpha;
    }
    // P @ V  (V^T fragment reads are contiguous b128 from global)
#pragma unroll
    for (int kc = 0; kc < 2; kc++) {
      bf16x8 pa = *(const bf16x8*)&sP[w][l16][kc * 32 + quad * 8];
#pragma unroll
      for (int dn = 0; dn < 4; dn++) {
        bf16x8 vb = *(const bf16x8*)(Vt + base + (size_t)(dn * 16 + l16) * 2048 + kt +
                                     kc * 32 + quad * 8);
        o[dn] = __builtin_amdgcn_mfma_f32_16x16x32_bf16(pa, vb, o[dn], 0, 0, 0);
      }
    }
  }

  float* op = split ? o1 : out;
  float* mlp = ml + (size_t)split * 131072;  // [m, l] pair of 65536 arrays
#pragma unroll
  for (int r = 0; r < 4; r++) {
    int row = row0 + quad * 4 + r;
    size_t g = (size_t)hb * 2048 + row;
    if (l16 == 0) {
      mlp[g] = mr[r];
      mlp[65536 + g] = lr[r];
    }
#pragma unroll
    for (int dn = 0; dn < 4; dn++) op[g * 64 + dn * 16 + l16] = o[dn][r];
  }
}

// ---------------- combine the 2 kt-splits ----------------
__global__ __launch_bounds__(256) void k_combine(const u16* __restrict__ ws,
                                                 float* __restrict__ out) {
  const float* o1 = (const float*)(ws + O1_E);
  const float* ml = (const float*)(ws + ML_E);
  size_t idx = (size_t)blockIdx.x * 256 + threadIdx.x;  // float4 index, 1M total
  size_t g = idx >> 4;                                  // row id (64 floats = 16 float4)
  float m0 = ml[g], l0 = ml[65536 + g];
  float m1 = ml[131072 + g], l1 = ml[196608 + g];
  float M = fmaxf(m0, m1);
  float w0 = __expf(m0 - M), w1 = __expf(m1 - M);
  float inv = 1.f / (l0 * w0 + l1 * w1);
  float4 a = ((const float4*)out)[idx];
  float4 b = ((const float4*)o1)[idx];
  float4 r;
  r.x = (a.x * w0 + b.x * w1) * inv;
  r.y = (a.y * w0 + b.y * w1) * inv;
  r.z = (a.z * w0 + b.z * w1) * inv;
  r.w = (a.w * w0 + b.w * w1) * inv;
  ((float4*)out)[idx] = r;
}

extern "C" void kernel_launch(void* const* d_in, const int* in_sizes, int n_in,
                              void* d_out, int out_size, void* d_ws, size_t ws_size,
                              hipStream_t stream) {
  const float* X = (const float*)d_in[0];
  const float* Wq = (const float*)d_in[1];
  const float* Wk = (const float*)d_in[2];
  const float* Wv = (const float*)d_in[3];
  u16* ws = (u16*)d_ws;
  float* out = (float*)d_out;

  k_xsplit<<<dim3(2048), dim3(256), 0, stream>>>(X, ws);
  k_wsplit<<<dim3(32, 32, 3), dim3(256), 0, stream>>>(Wq, Wk, Wv, ws);
  k_proj<<<dim3(8, 32, 3), dim3(256), 0, stream>>>(ws);
  k_attn<<<dim3(2048), dim3(256), 0, stream>>>(ws, out);
  k_combine<<<dim3(4096), dim3(256), 0, stream>>>(ws, out);
}

// Round 3
// 302.861 us; speedup vs baseline: 1.7072x; 1.7072x over previous
//
#include <hip/hip_runtime.h>

typedef unsigned short u16;
typedef unsigned int u32;
typedef __bf16 bf16x8 __attribute__((ext_vector_type(8)));
typedef float f32x4 __attribute__((ext_vector_type(4)));

// workspace offsets in u16 elements
#define WT_HI_E  ((size_t)0)             // 3 x 1M
#define WT_LO_E  ((size_t)3 << 20)
#define X_HI_E   ((size_t)6 << 20)       // 4M each below
#define X_LO_E   ((size_t)10 << 20)
#define Q_HI_E   ((size_t)14 << 20)
#define Q_LO_E   ((size_t)18 << 20)
#define K_HI_E   ((size_t)22 << 20)
#define K_LO_E   ((size_t)26 << 20)
#define V_HI_E   ((size_t)30 << 20)      // V^T layout [hb][d][s]; ends at 34M u16 = 68 MB

__device__ __forceinline__ u16 bf16_rne(float x) {
  u32 u = __float_as_uint(x);
  u32 r = (u + 0x7fffu + ((u >> 16) & 1u)) >> 16;
  return (u16)r;
}
__device__ __forceinline__ float bf16_f(u16 h) {
  return __uint_as_float(((u32)h) << 16);
}

__device__ __forceinline__ void gload16(const u16* g, u16* l) {
  __builtin_amdgcn_global_load_lds(
      (const __attribute__((address_space(1))) void*)g,
      (__attribute__((address_space(3))) void*)l, 16, 0, 0);
}

// ---------------- X split: fp32 -> bf16 hi/lo ----------------
__global__ __launch_bounds__(256) void k_xsplit(const float* __restrict__ X,
                                                u16* __restrict__ ws) {
  u16* xh = ws + X_HI_E;
  u16* xl = ws + X_LO_E;
  size_t i = ((size_t)blockIdx.x * 256 + threadIdx.x) * 8;
  float4 a = *(const float4*)(X + i);
  float4 b = *(const float4*)(X + i + 4);
  float v[8] = {a.x, a.y, a.z, a.w, b.x, b.y, b.z, b.w};
  u32 Hh[4], Ll[4];
#pragma unroll
  for (int j = 0; j < 4; j++) {
    u16 h0 = bf16_rne(v[2 * j]);
    u16 l0 = bf16_rne(v[2 * j] - bf16_f(h0));
    u16 h1 = bf16_rne(v[2 * j + 1]);
    u16 l1 = bf16_rne(v[2 * j + 1] - bf16_f(h1));
    Hh[j] = (u32)h0 | ((u32)h1 << 16);
    Ll[j] = (u32)l0 | ((u32)l1 << 16);
  }
  *(uint4*)(xh + i) = make_uint4(Hh[0], Hh[1], Hh[2], Hh[3]);
  *(uint4*)(xl + i) = make_uint4(Ll[0], Ll[1], Ll[2], Ll[3]);
}

// ---------------- W transpose + split: W[k][n] -> Wt_hi/lo[n][k] ----------------
__global__ __launch_bounds__(256) void k_wsplit(const float* __restrict__ w0,
                                                const float* __restrict__ w1,
                                                const float* __restrict__ w2,
                                                u16* __restrict__ ws) {
  int z = blockIdx.z;
  const float* W = (z == 0) ? w0 : ((z == 1) ? w1 : w2);
  u16* th = ws + WT_HI_E + (size_t)z * (1u << 20);
  u16* tl = ws + WT_LO_E + (size_t)z * (1u << 20);
  __shared__ float tile[32][33];
  int bx = blockIdx.x * 32, by = blockIdx.y * 32;
  int tx = threadIdx.x & 31, ty = threadIdx.x >> 5;  // 32 x 8
#pragma unroll
  for (int i = 0; i < 4; i++) {
    int r = ty + i * 8;
    tile[r][tx] = W[(size_t)(by + r) * 1024 + bx + tx];
  }
  __syncthreads();
#pragma unroll
  for (int i = 0; i < 4; i++) {
    int r = ty + i * 8;
    float v = tile[tx][r];  // = W[by+tx][bx+r]
    int n = bx + r, k = by + tx;
    u16 h = bf16_rne(v);
    u16 l = bf16_rne(v - bf16_f(h));
    th[(size_t)n * 1024 + k] = h;
    tl[(size_t)n * 1024 + k] = l;
  }
}

// ---------------- projections: Y = X @ W, compensated bf16 MFMA ----------------
// z=0 -> Q*0.125 (hi+lo), z=1 -> K (hi+lo), z=2 -> V (hi only, stored transposed).
// Q/K layout [h*2+b][s][d]; V layout [h*2+b][d][s].
__global__ __launch_bounds__(256) void k_proj(u16* __restrict__ ws) {
  int z = blockIdx.z;
  const u16* Xh = ws + X_HI_E;
  const u16* Xl = ws + X_LO_E;
  const u16* Wh = ws + WT_HI_E + (size_t)z * (1u << 20);
  const u16* Wl = ws + WT_LO_E + (size_t)z * (1u << 20);
  u16* dsth = ws + ((z == 0) ? Q_HI_E : ((z == 1) ? K_HI_E : V_HI_E));
  u16* dstl = (z == 0) ? (ws + Q_LO_E) : ((z == 1) ? (ws + K_LO_E) : (u16*)0);

  __shared__ u16 sXh[4096], sXl[4096], sWh[4096], sWl[4096];
  int M0 = blockIdx.y * 128, N0 = blockIdx.x * 128;
  int tid = threadIdx.x, lane = tid & 63, w = tid >> 6;
  int quad = lane >> 4, l16 = lane & 15;
  int mb = (w & 1) * 64, nb = (w >> 1) * 64;

  const f32x4 z4 = {0.f, 0.f, 0.f, 0.f};
  f32x4 acc[4][4];
#pragma unroll
  for (int i = 0; i < 4; i++)
#pragma unroll
    for (int j = 0; j < 4; j++) acc[i][j] = z4;

  for (int kk = 0; kk < 1024; kk += 32) {
    __syncthreads();
#pragma unroll
    for (int c2 = 0; c2 < 2; c2++) {
      int cb = c2 * 256 + w * 64;
      int c = cb + lane;
      int row = c >> 2, q8 = c & 3;
      size_t gx = (size_t)(M0 + row) * 1024 + kk + q8 * 8;
      size_t gw = (size_t)(N0 + row) * 1024 + kk + q8 * 8;
      gload16(Xh + gx, sXh + (size_t)cb * 8);
      gload16(Wh + gw, sWh + (size_t)cb * 8);
      if (z != 2) {
        gload16(Xl + gx, sXl + (size_t)cb * 8);
        gload16(Wl + gw, sWl + (size_t)cb * 8);
      }
    }
    __syncthreads();
    bf16x8 ah[4], bh[4];
#pragma unroll
    for (int i = 0; i < 4; i++) {
      ah[i] = *(const bf16x8*)&sXh[(mb + i * 16 + l16) * 32 + quad * 8];
      bh[i] = *(const bf16x8*)&sWh[(nb + i * 16 + l16) * 32 + quad * 8];
    }
    if (z != 2) {
      bf16x8 al[4], bl[4];
#pragma unroll
      for (int i = 0; i < 4; i++) {
        al[i] = *(const bf16x8*)&sXl[(mb + i * 16 + l16) * 32 + quad * 8];
        bl[i] = *(const bf16x8*)&sWl[(nb + i * 16 + l16) * 32 + quad * 8];
      }
#pragma unroll
      for (int i = 0; i < 4; i++)
#pragma unroll
        for (int j = 0; j < 4; j++) {
          f32x4 c0 = acc[i][j];
          c0 = __builtin_amdgcn_mfma_f32_16x16x32_bf16(ah[i], bh[j], c0, 0, 0, 0);
          c0 = __builtin_amdgcn_mfma_f32_16x16x32_bf16(ah[i], bl[j], c0, 0, 0, 0);
          c0 = __builtin_amdgcn_mfma_f32_16x16x32_bf16(al[i], bh[j], c0, 0, 0, 0);
          acc[i][j] = c0;
        }
    } else {
#pragma unroll
      for (int i = 0; i < 4; i++)
#pragma unroll
        for (int j = 0; j < 4; j++)
          acc[i][j] = __builtin_amdgcn_mfma_f32_16x16x32_bf16(ah[i], bh[j], acc[i][j], 0, 0, 0);
    }
  }

  if (z == 2) {
#pragma unroll
    for (int i = 0; i < 4; i++)
#pragma unroll
      for (int j = 0; j < 4; j++) {
        int mg = M0 + mb + i * 16 + quad * 4;
        int ng = N0 + nb + j * 16 + l16;
        int b = mg >> 11, s = mg & 2047;
        int hh = ng >> 6, d = ng & 63;
        u16 p0 = bf16_rne(acc[i][j][0]);
        u16 p1 = bf16_rne(acc[i][j][1]);
        u16 p2 = bf16_rne(acc[i][j][2]);
        u16 p3 = bf16_rne(acc[i][j][3]);
        *(uint2*)&dsth[((size_t)(hh * 2 + b) * 64 + d) * 2048 + s] =
            make_uint2((u32)p0 | ((u32)p1 << 16), (u32)p2 | ((u32)p3 << 16));
      }
  } else {
    float qscale = (z == 0) ? 0.125f : 1.0f;  // fold 1/sqrt(dh) into Q (exact pow2)
#pragma unroll
    for (int i = 0; i < 4; i++)
#pragma unroll
      for (int j = 0; j < 4; j++)
#pragma unroll
        for (int r = 0; r < 4; r++) {
          int mg = M0 + mb + i * 16 + quad * 4 + r;
          int ng = N0 + nb + j * 16 + l16;
          int b = mg >> 11, s = mg & 2047;
          int hh = ng >> 6, d = ng & 63;
          size_t idx = ((size_t)(hh * 2 + b) * 2048 + s) * 64 + d;
          float y = acc[i][j][r] * qscale;
          u16 h = bf16_rne(y);
          dsth[idx] = h;
          dstl[idx] = bf16_rne(y - bf16_f(h));
        }
  }
}

// ---------------- flash attention: LDS-staged, BQ=64, grid 1024 ----------------
// 4 waves/block, each wave owns 16 Q rows. K hi/lo + V^T tiles staged via
// global_load_lds into [kc][64][32] u16 sub-arrays (bank-optimal b128 reads,
// lane-contiguous for the LDS DMA). 4 blocks/CU (LDS 33.3 KB, VGPR<=128).
__global__ __launch_bounds__(256, 4) void k_attn(u16* __restrict__ ws,
                                                 float* __restrict__ out) {
  const u16* Qh = ws + Q_HI_E;
  const u16* Ql = ws + Q_LO_E;
  const u16* Kh = ws + K_HI_E;
  const u16* Kl = ws + K_LO_E;
  const u16* Vt = ws + V_HI_E;

  __shared__ u16 sKh[2][64][32], sKl[2][64][32], sVt[2][64][32];  // 24 KB
  __shared__ u16 sP[4][16][68];                                   // 8.5 KB, pad 68

  // hb = id&31: per-XCD (id&7) locality over 4 hb values (~3 MB K+V in L2)
  int id = blockIdx.x;
  int hb = id & 31, qb = id >> 5;
  int q0 = qb * 64;

  int tid = threadIdx.x, w = tid >> 6, lane = tid & 63;
  int quad = lane >> 4, l16 = lane & 15;
  size_t base = (size_t)hb * (2048 * 64);
  int row0 = q0 + w * 16;

  bf16x8 qh[2], ql[2];
#pragma unroll
  for (int kc = 0; kc < 2; kc++) {
    size_t off = base + (size_t)(row0 + l16) * 64 + kc * 32 + quad * 8;
    qh[kc] = *(const bf16x8*)(Qh + off);
    ql[kc] = *(const bf16x8*)(Ql + off);
  }
  const f32x4 z4 = {0.f, 0.f, 0.f, 0.f};
  float mr[4], lr[4];
  f32x4 o[4];
#pragma unroll
  for (int dn = 0; dn < 4; dn++) o[dn] = z4;
#pragma unroll
  for (int r = 0; r < 4; r++) {
    mr[r] = -1e30f;
    lr[r] = 0.f;
  }

  int srow = w * 16 + (lane >> 2);  // staging row this lane covers
  int sch = lane & 3;               // 16B chunk within 32-u16 row

  for (int kt = 0; kt < 2048; kt += 64) {
    __syncthreads();
    // stage K hi/lo [kc][key][d-half] and V^T [kc][d][key-half]; 1 KB per wave-load
#pragma unroll
    for (int kc = 0; kc < 2; kc++) {
      size_t kg = base + (size_t)(kt + srow) * 64 + kc * 32 + sch * 8;
      gload16(Kh + kg, &sKh[kc][w * 16][0]);
      gload16(Kl + kg, &sKl[kc][w * 16][0]);
      size_t vg = base + (size_t)srow * 2048 + kt + kc * 32 + sch * 8;
      gload16(Vt + vg, &sVt[kc][w * 16][0]);
    }
    __syncthreads();

    f32x4 sc[4] = {z4, z4, z4, z4};
#pragma unroll
    for (int kc = 0; kc < 2; kc++) {
      bf16x8 kh[4], klo[4];
#pragma unroll
      for (int nt = 0; nt < 4; nt++) {
        kh[nt] = *(const bf16x8*)&sKh[kc][nt * 16 + l16][quad * 8];
        klo[nt] = *(const bf16x8*)&sKl[kc][nt * 16 + l16][quad * 8];
      }
#pragma unroll
      for (int nt = 0; nt < 4; nt++) {
        f32x4 a = sc[nt];
        a = __builtin_amdgcn_mfma_f32_16x16x32_bf16(qh[kc], kh[nt], a, 0, 0, 0);
        a = __builtin_amdgcn_mfma_f32_16x16x32_bf16(qh[kc], klo[nt], a, 0, 0, 0);
        a = __builtin_amdgcn_mfma_f32_16x16x32_bf16(ql[kc], kh[nt], a, 0, 0, 0);
        sc[nt] = a;
      }
    }
    // online softmax (scale folded into Q at proj time)
#pragma unroll
    for (int r = 0; r < 4; r++) {
      float m1v = fmaxf(fmaxf(sc[0][r], sc[1][r]), fmaxf(sc[2][r], sc[3][r]));
#pragma unroll
      for (int off = 1; off < 16; off <<= 1) m1v = fmaxf(m1v, __shfl_xor(m1v, off));
      float mnew = fmaxf(mr[r], m1v);
      float alpha = __expf(mr[r] - mnew);
      mr[r] = mnew;
      float rs = 0.f;
#pragma unroll
      for (int nt = 0; nt < 4; nt++) {
        float p = __expf(sc[nt][r] - mnew);
        rs += p;
        sP[w][quad * 4 + r][nt * 16 + l16] = bf16_rne(p);
      }
#pragma unroll
      for (int off = 1; off < 16; off <<= 1) rs += __shfl_xor(rs, off);
      lr[r] = lr[r] * alpha + rs;
#pragma unroll
      for (int dn = 0; dn < 4; dn++) o[dn][r] *= alpha;
    }
    // P @ V (wave-private sP round-trip: C-layout -> A-layout)
#pragma unroll
    for (int kc = 0; kc < 2; kc++) {
      bf16x8 pa = *(const bf16x8*)&sP[w][l16][kc * 32 + quad * 8];
#pragma unroll
      for (int dn = 0; dn < 4; dn++) {
        bf16x8 vb = *(const bf16x8*)&sVt[kc][dn * 16 + l16][quad * 8];
        o[dn] = __builtin_amdgcn_mfma_f32_16x16x32_bf16(pa, vb, o[dn], 0, 0, 0);
      }
    }
  }

#pragma unroll
  for (int r = 0; r < 4; r++) {
    int row = row0 + quad * 4 + r;
    size_t g = (size_t)hb * 2048 + row;
    float inv = 1.f / lr[r];
#pragma unroll
    for (int dn = 0; dn < 4; dn++) out[g * 64 + dn * 16 + l16] = o[dn][r] * inv;
  }
}

extern "C" void kernel_launch(void* const* d_in, const int* in_sizes, int n_in,
                              void* d_out, int out_size, void* d_ws, size_t ws_size,
                              hipStream_t stream) {
  const float* X = (const float*)d_in[0];
  const float* Wq = (const float*)d_in[1];
  const float* Wk = (const float*)d_in[2];
  const float* Wv = (const float*)d_in[3];
  u16* ws = (u16*)d_ws;
  float* out = (float*)d_out;

  k_xsplit<<<dim3(2048), dim3(256), 0, stream>>>(X, ws);
  k_wsplit<<<dim3(32, 32, 3), dim3(256), 0, stream>>>(Wq, Wk, Wv, ws);
  k_proj<<<dim3(8, 32, 3), dim3(256), 0, stream>>>(ws);
  k_attn<<<dim3(1024), dim3(256), 0, stream>>>(ws, out);
}

// Round 4
// 263.602 us; speedup vs baseline: 1.9614x; 1.1489x over previous
//
#include <hip/hip_runtime.h>

typedef unsigned short u16;
typedef unsigned int u32;
typedef __bf16 bf16x8 __attribute__((ext_vector_type(8)));
typedef float f32x4 __attribute__((ext_vector_type(4)));

// workspace offsets in u16 elements
#define WT_HI_E  ((size_t)0)             // 3 x 1M
#define WT_LO_E  ((size_t)3 << 20)
#define X_HI_E   ((size_t)6 << 20)       // 4M each below
#define X_LO_E   ((size_t)10 << 20)
#define Q_HI_E   ((size_t)14 << 20)
#define Q_LO_E   ((size_t)18 << 20)
#define K_HI_E   ((size_t)22 << 20)
#define K_LO_E   ((size_t)26 << 20)
#define V_HI_E   ((size_t)30 << 20)      // V^T layout [hb][d][s]; ends at 34M u16 = 68 MB

__device__ __forceinline__ u16 bf16_rne(float x) {
  u32 u = __float_as_uint(x);
  u32 r = (u + 0x7fffu + ((u >> 16) & 1u)) >> 16;
  return (u16)r;
}
__device__ __forceinline__ float bf16_f(u16 h) {
  return __uint_as_float(((u32)h) << 16);
}

__device__ __forceinline__ void gload16(const u16* g, u16* l) {
  __builtin_amdgcn_global_load_lds(
      (const __attribute__((address_space(1))) void*)g,
      (__attribute__((address_space(3))) void*)l, 16, 0, 0);
}

// ---------------- X split: fp32 -> bf16 hi/lo ----------------
__global__ __launch_bounds__(256) void k_xsplit(const float* __restrict__ X,
                                                u16* __restrict__ ws) {
  u16* xh = ws + X_HI_E;
  u16* xl = ws + X_LO_E;
  size_t i = ((size_t)blockIdx.x * 256 + threadIdx.x) * 8;
  float4 a = *(const float4*)(X + i);
  float4 b = *(const float4*)(X + i + 4);
  float v[8] = {a.x, a.y, a.z, a.w, b.x, b.y, b.z, b.w};
  u32 Hh[4], Ll[4];
#pragma unroll
  for (int j = 0; j < 4; j++) {
    u16 h0 = bf16_rne(v[2 * j]);
    u16 l0 = bf16_rne(v[2 * j] - bf16_f(h0));
    u16 h1 = bf16_rne(v[2 * j + 1]);
    u16 l1 = bf16_rne(v[2 * j + 1] - bf16_f(h1));
    Hh[j] = (u32)h0 | ((u32)h1 << 16);
    Ll[j] = (u32)l0 | ((u32)l1 << 16);
  }
  *(uint4*)(xh + i) = make_uint4(Hh[0], Hh[1], Hh[2], Hh[3]);
  *(uint4*)(xl + i) = make_uint4(Ll[0], Ll[1], Ll[2], Ll[3]);
}

// ---------------- W transpose + split: W[k][n] -> Wt_hi/lo[n][k] ----------------
__global__ __launch_bounds__(256) void k_wsplit(const float* __restrict__ w0,
                                                const float* __restrict__ w1,
                                                const float* __restrict__ w2,
                                                u16* __restrict__ ws) {
  int z = blockIdx.z;
  const float* W = (z == 0) ? w0 : ((z == 1) ? w1 : w2);
  u16* th = ws + WT_HI_E + (size_t)z * (1u << 20);
  u16* tl = ws + WT_LO_E + (size_t)z * (1u << 20);
  __shared__ float tile[32][33];
  int bx = blockIdx.x * 32, by = blockIdx.y * 32;
  int tx = threadIdx.x & 31, ty = threadIdx.x >> 5;  // 32 x 8
#pragma unroll
  for (int i = 0; i < 4; i++) {
    int r = ty + i * 8;
    tile[r][tx] = W[(size_t)(by + r) * 1024 + bx + tx];
  }
  __syncthreads();
#pragma unroll
  for (int i = 0; i < 4; i++) {
    int r = ty + i * 8;
    float v = tile[tx][r];  // = W[by+tx][bx+r]
    int n = bx + r, k = by + tx;
    u16 h = bf16_rne(v);
    u16 l = bf16_rne(v - bf16_f(h));
    th[(size_t)n * 1024 + k] = h;
    tl[(size_t)n * 1024 + k] = l;
  }
}

// ---------------- projections: Y = X @ W, compensated bf16 MFMA ----------------
// z=0 -> Q*0.125 (hi+lo), z=1 -> K (hi+lo), z=2 -> V (hi only, stored transposed).
// Q/K layout [h*2+b][s][d]; V layout [h*2+b][d][s].
__global__ __launch_bounds__(256) void k_proj(u16* __restrict__ ws) {
  int z = blockIdx.z;
  const u16* Xh = ws + X_HI_E;
  const u16* Xl = ws + X_LO_E;
  const u16* Wh = ws + WT_HI_E + (size_t)z * (1u << 20);
  const u16* Wl = ws + WT_LO_E + (size_t)z * (1u << 20);
  u16* dsth = ws + ((z == 0) ? Q_HI_E : ((z == 1) ? K_HI_E : V_HI_E));
  u16* dstl = (z == 0) ? (ws + Q_LO_E) : ((z == 1) ? (ws + K_LO_E) : (u16*)0);

  __shared__ u16 sXh[4096], sXl[4096], sWh[4096], sWl[4096];
  int M0 = blockIdx.y * 128, N0 = blockIdx.x * 128;
  int tid = threadIdx.x, lane = tid & 63, w = tid >> 6;
  int quad = lane >> 4, l16 = lane & 15;
  int mb = (w & 1) * 64, nb = (w >> 1) * 64;

  const f32x4 z4 = {0.f, 0.f, 0.f, 0.f};
  f32x4 acc[4][4];
#pragma unroll
  for (int i = 0; i < 4; i++)
#pragma unroll
    for (int j = 0; j < 4; j++) acc[i][j] = z4;

  for (int kk = 0; kk < 1024; kk += 32) {
    __syncthreads();
#pragma unroll
    for (int c2 = 0; c2 < 2; c2++) {
      int cb = c2 * 256 + w * 64;
      int c = cb + lane;
      int row = c >> 2, q8 = c & 3;
      size_t gx = (size_t)(M0 + row) * 1024 + kk + q8 * 8;
      size_t gw = (size_t)(N0 + row) * 1024 + kk + q8 * 8;
      gload16(Xh + gx, sXh + (size_t)cb * 8);
      gload16(Wh + gw, sWh + (size_t)cb * 8);
      if (z != 2) {
        gload16(Xl + gx, sXl + (size_t)cb * 8);
        gload16(Wl + gw, sWl + (size_t)cb * 8);
      }
    }
    __syncthreads();
    bf16x8 ah[4], bh[4];
#pragma unroll
    for (int i = 0; i < 4; i++) {
      ah[i] = *(const bf16x8*)&sXh[(mb + i * 16 + l16) * 32 + quad * 8];
      bh[i] = *(const bf16x8*)&sWh[(nb + i * 16 + l16) * 32 + quad * 8];
    }
    if (z != 2) {
      bf16x8 al[4], bl[4];
#pragma unroll
      for (int i = 0; i < 4; i++) {
        al[i] = *(const bf16x8*)&sXl[(mb + i * 16 + l16) * 32 + quad * 8];
        bl[i] = *(const bf16x8*)&sWl[(nb + i * 16 + l16) * 32 + quad * 8];
      }
#pragma unroll
      for (int i = 0; i < 4; i++)
#pragma unroll
        for (int j = 0; j < 4; j++) {
          f32x4 c0 = acc[i][j];
          c0 = __builtin_amdgcn_mfma_f32_16x16x32_bf16(ah[i], bh[j], c0, 0, 0, 0);
          c0 = __builtin_amdgcn_mfma_f32_16x16x32_bf16(ah[i], bl[j], c0, 0, 0, 0);
          c0 = __builtin_amdgcn_mfma_f32_16x16x32_bf16(al[i], bh[j], c0, 0, 0, 0);
          acc[i][j] = c0;
        }
    } else {
#pragma unroll
      for (int i = 0; i < 4; i++)
#pragma unroll
        for (int j = 0; j < 4; j++)
          acc[i][j] = __builtin_amdgcn_mfma_f32_16x16x32_bf16(ah[i], bh[j], acc[i][j], 0, 0, 0);
    }
  }

  if (z == 2) {
#pragma unroll
    for (int i = 0; i < 4; i++)
#pragma unroll
      for (int j = 0; j < 4; j++) {
        int mg = M0 + mb + i * 16 + quad * 4;
        int ng = N0 + nb + j * 16 + l16;
        int b = mg >> 11, s = mg & 2047;
        int hh = ng >> 6, d = ng & 63;
        u16 p0 = bf16_rne(acc[i][j][0]);
        u16 p1 = bf16_rne(acc[i][j][1]);
        u16 p2 = bf16_rne(acc[i][j][2]);
        u16 p3 = bf16_rne(acc[i][j][3]);
        *(uint2*)&dsth[((size_t)(hh * 2 + b) * 64 + d) * 2048 + s] =
            make_uint2((u32)p0 | ((u32)p1 << 16), (u32)p2 | ((u32)p3 << 16));
      }
  } else {
    float qscale = (z == 0) ? 0.125f : 1.0f;  // fold 1/sqrt(dh) into Q (exact pow2)
#pragma unroll
    for (int i = 0; i < 4; i++)
#pragma unroll
      for (int j = 0; j < 4; j++)
#pragma unroll
        for (int r = 0; r < 4; r++) {
          int mg = M0 + mb + i * 16 + quad * 4 + r;
          int ng = N0 + nb + j * 16 + l16;
          int b = mg >> 11, s = mg & 2047;
          int hh = ng >> 6, d = ng & 63;
          size_t idx = ((size_t)(hh * 2 + b) * 2048 + s) * 64 + d;
          float y = acc[i][j][r] * qscale;
          u16 h = bf16_rne(y);
          dsth[idx] = h;
          dstl[idx] = bf16_rne(y - bf16_f(h));
        }
  }
}

// ---------------- flash attention: S^T = K·Q^T variant ----------------
// 4 waves/block, each wave owns 16 Q rows (query = l16 in all fragments).
// S^T C-layout puts 4 consecutive KEYS per lane -> sP writes are b64,
// A-operand reads are contiguous b128; softmax reduces over quads (2 shfl).
__global__ __launch_bounds__(256, 4) void k_attn(u16* __restrict__ ws,
                                                 float* __restrict__ out) {
  const u16* Qh = ws + Q_HI_E;
  const u16* Ql = ws + Q_LO_E;
  const u16* Kh = ws + K_HI_E;
  const u16* Kl = ws + K_LO_E;
  const u16* Vt = ws + V_HI_E;

  __shared__ u16 sKh[2][64][32], sKl[2][64][32], sVt[2][64][32];  // 24 KB
  __shared__ u16 sP[4][16][72];  // wave-private [query][key]; 144B rows (16B-aligned)

  int id = blockIdx.x;
  int hb = id & 31, qb = id >> 5;
  int q0 = qb * 64;

  int tid = threadIdx.x, w = tid >> 6, lane = tid & 63;
  int quad = lane >> 4, l16 = lane & 15;
  size_t base = (size_t)hb * (2048 * 64);
  int row0 = q0 + w * 16;

  bf16x8 qh[2], ql[2];  // B-operand: n = query = l16
#pragma unroll
  for (int kc = 0; kc < 2; kc++) {
    size_t off = base + (size_t)(row0 + l16) * 64 + kc * 32 + quad * 8;
    qh[kc] = *(const bf16x8*)(Qh + off);
    ql[kc] = *(const bf16x8*)(Ql + off);
  }
  const f32x4 z4 = {0.f, 0.f, 0.f, 0.f};
  float mr = -1e30f, lr = 0.f;  // stats for query l16 (scalar per lane)
  f32x4 o[4];
#pragma unroll
  for (int dn = 0; dn < 4; dn++) o[dn] = z4;

  int srow = w * 16 + (lane >> 2);  // staging row this lane covers
  int sch = lane & 3;               // 16B chunk within 32-u16 row

  for (int kt = 0; kt < 2048; kt += 64) {
    __syncthreads();
#pragma unroll
    for (int kc = 0; kc < 2; kc++) {
      size_t kg = base + (size_t)(kt + srow) * 64 + kc * 32 + sch * 8;
      gload16(Kh + kg, &sKh[kc][w * 16][0]);
      gload16(Kl + kg, &sKl[kc][w * 16][0]);
      size_t vg = base + (size_t)srow * 2048 + kt + kc * 32 + sch * 8;
      gload16(Vt + vg, &sVt[kc][w * 16][0]);
    }
    __syncthreads();

    // S^T = K·Q^T (A = K rows, B = Q rows); lane holds keys nt*16+quad*4+r, query l16
    f32x4 sc[4] = {z4, z4, z4, z4};
#pragma unroll
    for (int kc = 0; kc < 2; kc++) {
      bf16x8 kh[4], klo[4];
#pragma unroll
      for (int nt = 0; nt < 4; nt++) {
        kh[nt] = *(const bf16x8*)&sKh[kc][nt * 16 + l16][quad * 8];
        klo[nt] = *(const bf16x8*)&sKl[kc][nt * 16 + l16][quad * 8];
      }
#pragma unroll
      for (int nt = 0; nt < 4; nt++) {
        f32x4 a = sc[nt];
        a = __builtin_amdgcn_mfma_f32_16x16x32_bf16(kh[nt], qh[kc], a, 0, 0, 0);
        a = __builtin_amdgcn_mfma_f32_16x16x32_bf16(kh[nt], ql[kc], a, 0, 0, 0);
        a = __builtin_amdgcn_mfma_f32_16x16x32_bf16(klo[nt], qh[kc], a, 0, 0, 0);
        sc[nt] = a;
      }
    }
    // online softmax for query l16: 16 in-lane keys, then reduce across quads
    float m1v = sc[0][0];
#pragma unroll
    for (int nt = 0; nt < 4; nt++)
#pragma unroll
      for (int r = 0; r < 4; r++) m1v = fmaxf(m1v, sc[nt][r]);
    m1v = fmaxf(m1v, __shfl_xor(m1v, 16));
    m1v = fmaxf(m1v, __shfl_xor(m1v, 32));
    float mnew = fmaxf(mr, m1v);
    float alpha = __expf(mr - mnew);
    mr = mnew;
    float rs = 0.f;
#pragma unroll
    for (int nt = 0; nt < 4; nt++) {
      float p0 = __expf(sc[nt][0] - mnew);
      float p1 = __expf(sc[nt][1] - mnew);
      float p2 = __expf(sc[nt][2] - mnew);
      float p3 = __expf(sc[nt][3] - mnew);
      rs += (p0 + p1) + (p2 + p3);
      *(uint2*)&sP[w][l16][nt * 16 + quad * 4] =
          make_uint2((u32)bf16_rne(p0) | ((u32)bf16_rne(p1) << 16),
                     (u32)bf16_rne(p2) | ((u32)bf16_rne(p3) << 16));
    }
    rs += __shfl_xor(rs, 16);
    rs += __shfl_xor(rs, 32);
    lr = lr * alpha + rs;
    // redistribute alpha to O-rows (query = quad*4+r in C-layout)
    float af[4];
#pragma unroll
    for (int r = 0; r < 4; r++) af[r] = __shfl(alpha, quad * 20 + r);
#pragma unroll
    for (int dn = 0; dn < 4; dn++)
#pragma unroll
      for (int r = 0; r < 4; r++) o[dn][r] *= af[r];
    // P @ V: A = P[query=l16][key contiguous], B = V^T rows
#pragma unroll
    for (int kc = 0; kc < 2; kc++) {
      bf16x8 pa = *(const bf16x8*)&sP[w][l16][kc * 32 + quad * 8];
#pragma unroll
      for (int dn = 0; dn < 4; dn++) {
        bf16x8 vb = *(const bf16x8*)&sVt[kc][dn * 16 + l16][quad * 8];
        o[dn] = __builtin_amdgcn_mfma_f32_16x16x32_bf16(pa, vb, o[dn], 0, 0, 0);
      }
    }
  }

  float lf[4];
#pragma unroll
  for (int r = 0; r < 4; r++) lf[r] = __shfl(lr, quad * 20 + r);
#pragma unroll
  for (int r = 0; r < 4; r++) {
    int row = row0 + quad * 4 + r;
    size_t g = (size_t)hb * 2048 + row;
    float inv = 1.f / lf[r];
#pragma unroll
    for (int dn = 0; dn < 4; dn++) out[g * 64 + dn * 16 + l16] = o[dn][r] * inv;
  }
}

extern "C" void kernel_launch(void* const* d_in, const int* in_sizes, int n_in,
                              void* d_out, int out_size, void* d_ws, size_t ws_size,
                              hipStream_t stream) {
  const float* X = (const float*)d_in[0];
  const float* Wq = (const float*)d_in[1];
  const float* Wk = (const float*)d_in[2];
  const float* Wv = (const float*)d_in[3];
  u16* ws = (u16*)d_ws;
  float* out = (float*)d_out;

  k_xsplit<<<dim3(2048), dim3(256), 0, stream>>>(X, ws);
  k_wsplit<<<dim3(32, 32, 3), dim3(256), 0, stream>>>(Wq, Wk, Wv, ws);
  k_proj<<<dim3(8, 32, 3), dim3(256), 0, stream>>>(ws);
  k_attn<<<dim3(1024), dim3(256), 0, stream>>>(ws, out);
}

// Round 5
// 243.268 us; speedup vs baseline: 2.1254x; 1.0836x over previous
//
#include <hip/hip_runtime.h>

typedef unsigned short u16;
typedef unsigned int u32;
typedef __bf16 bf16x8 __attribute__((ext_vector_type(8)));
typedef float f32x4 __attribute__((ext_vector_type(4)));
typedef float f32x16 __attribute__((ext_vector_type(16)));

// workspace offsets in u16 elements
#define WT_HI_E  ((size_t)0)             // 3 x 1M
#define WT_LO_E  ((size_t)3 << 20)
#define X_HI_E   ((size_t)6 << 20)       // 4M each below
#define X_LO_E   ((size_t)10 << 20)
#define Q_HI_E   ((size_t)14 << 20)
#define Q_LO_E   ((size_t)18 << 20)
#define K_HI_E   ((size_t)22 << 20)      // [hb][s][64] d-chunk-XOR-swizzled
#define K_LO_E   ((size_t)26 << 20)
#define V_HI_E   ((size_t)30 << 20)      // V^T [hb][d][2048], s-chunk-XOR-swizzled per 64-key block

__device__ __forceinline__ u16 bf16_rne(float x) {
  u32 u = __float_as_uint(x);
  u32 r = (u + 0x7fffu + ((u >> 16) & 1u)) >> 16;
  return (u16)r;
}
__device__ __forceinline__ float bf16_f(u16 h) {
  return __uint_as_float(((u32)h) << 16);
}

__device__ __forceinline__ void gload16(const u16* g, u16* l) {
  __builtin_amdgcn_global_load_lds(
      (const __attribute__((address_space(1))) void*)g,
      (__attribute__((address_space(3))) void*)l, 16, 0, 0);
}

// ---------------- X split: fp32 -> bf16 hi/lo ----------------
__global__ __launch_bounds__(256) void k_xsplit(const float* __restrict__ X,
                                                u16* __restrict__ ws) {
  u16* xh = ws + X_HI_E;
  u16* xl = ws + X_LO_E;
  size_t i = ((size_t)blockIdx.x * 256 + threadIdx.x) * 8;
  float4 a = *(const float4*)(X + i);
  float4 b = *(const float4*)(X + i + 4);
  float v[8] = {a.x, a.y, a.z, a.w, b.x, b.y, b.z, b.w};
  u32 Hh[4], Ll[4];
#pragma unroll
  for (int j = 0; j < 4; j++) {
    u16 h0 = bf16_rne(v[2 * j]);
    u16 l0 = bf16_rne(v[2 * j] - bf16_f(h0));
    u16 h1 = bf16_rne(v[2 * j + 1]);
    u16 l1 = bf16_rne(v[2 * j + 1] - bf16_f(h1));
    Hh[j] = (u32)h0 | ((u32)h1 << 16);
    Ll[j] = (u32)l0 | ((u32)l1 << 16);
  }
  *(uint4*)(xh + i) = make_uint4(Hh[0], Hh[1], Hh[2], Hh[3]);
  *(uint4*)(xl + i) = make_uint4(Ll[0], Ll[1], Ll[2], Ll[3]);
}

// ---------------- W transpose + split: W[k][n] -> Wt_hi/lo[n][k] ----------------
__global__ __launch_bounds__(256) void k_wsplit(const float* __restrict__ w0,
                                                const float* __restrict__ w1,
                                                const float* __restrict__ w2,
                                                u16* __restrict__ ws) {
  int z = blockIdx.z;
  const float* W = (z == 0) ? w0 : ((z == 1) ? w1 : w2);
  u16* th = ws + WT_HI_E + (size_t)z * (1u << 20);
  u16* tl = ws + WT_LO_E + (size_t)z * (1u << 20);
  __shared__ float tile[32][33];
  int bx = blockIdx.x * 32, by = blockIdx.y * 32;
  int tx = threadIdx.x & 31, ty = threadIdx.x >> 5;  // 32 x 8
#pragma unroll
  for (int i = 0; i < 4; i++) {
    int r = ty + i * 8;
    tile[r][tx] = W[(size_t)(by + r) * 1024 + bx + tx];
  }
  __syncthreads();
#pragma unroll
  for (int i = 0; i < 4; i++) {
    int r = ty + i * 8;
    float v = tile[tx][r];  // = W[by+tx][bx+r]
    int n = bx + r, k = by + tx;
    u16 h = bf16_rne(v);
    u16 l = bf16_rne(v - bf16_f(h));
    th[(size_t)n * 1024 + k] = h;
    tl[(size_t)n * 1024 + k] = l;
  }
}

// ---------------- projections: Y = X @ W, compensated bf16 MFMA ----------------
// z=0 -> Q*0.125 (hi+lo, linear), z=1 -> K (hi+lo, d-chunk swizzled),
// z=2 -> V (hi only, stored transposed, s-chunk swizzled per 64-key block).
__global__ __launch_bounds__(256) void k_proj(u16* __restrict__ ws) {
  int z = blockIdx.z;
  const u16* Xh = ws + X_HI_E;
  const u16* Xl = ws + X_LO_E;
  const u16* Wh = ws + WT_HI_E + (size_t)z * (1u << 20);
  const u16* Wl = ws + WT_LO_E + (size_t)z * (1u << 20);
  u16* dsth = ws + ((z == 0) ? Q_HI_E : ((z == 1) ? K_HI_E : V_HI_E));
  u16* dstl = (z == 0) ? (ws + Q_LO_E) : ((z == 1) ? (ws + K_LO_E) : (u16*)0);

  __shared__ u16 sXh[4096], sXl[4096], sWh[4096], sWl[4096];
  int M0 = blockIdx.y * 128, N0 = blockIdx.x * 128;
  int tid = threadIdx.x, lane = tid & 63, w = tid >> 6;
  int quad = lane >> 4, l16 = lane & 15;
  int mb = (w & 1) * 64, nb = (w >> 1) * 64;

  const f32x4 z4 = {0.f, 0.f, 0.f, 0.f};
  f32x4 acc[4][4];
#pragma unroll
  for (int i = 0; i < 4; i++)
#pragma unroll
    for (int j = 0; j < 4; j++) acc[i][j] = z4;

  for (int kk = 0; kk < 1024; kk += 32) {
    __syncthreads();
#pragma unroll
    for (int c2 = 0; c2 < 2; c2++) {
      int cb = c2 * 256 + w * 64;
      int c = cb + lane;
      int row = c >> 2, q8 = c & 3;
      size_t gx = (size_t)(M0 + row) * 1024 + kk + q8 * 8;
      size_t gw = (size_t)(N0 + row) * 1024 + kk + q8 * 8;
      gload16(Xh + gx, sXh + (size_t)cb * 8);
      gload16(Wh + gw, sWh + (size_t)cb * 8);
      if (z != 2) {
        gload16(Xl + gx, sXl + (size_t)cb * 8);
        gload16(Wl + gw, sWl + (size_t)cb * 8);
      }
    }
    __syncthreads();
    bf16x8 ah[4], bh[4];
#pragma unroll
    for (int i = 0; i < 4; i++) {
      ah[i] = *(const bf16x8*)&sXh[(mb + i * 16 + l16) * 32 + quad * 8];
      bh[i] = *(const bf16x8*)&sWh[(nb + i * 16 + l16) * 32 + quad * 8];
    }
    if (z != 2) {
      bf16x8 al[4], bl[4];
#pragma unroll
      for (int i = 0; i < 4; i++) {
        al[i] = *(const bf16x8*)&sXl[(mb + i * 16 + l16) * 32 + quad * 8];
        bl[i] = *(const bf16x8*)&sWl[(nb + i * 16 + l16) * 32 + quad * 8];
      }
#pragma unroll
      for (int i = 0; i < 4; i++)
#pragma unroll
        for (int j = 0; j < 4; j++) {
          f32x4 c0 = acc[i][j];
          c0 = __builtin_amdgcn_mfma_f32_16x16x32_bf16(ah[i], bh[j], c0, 0, 0, 0);
          c0 = __builtin_amdgcn_mfma_f32_16x16x32_bf16(ah[i], bl[j], c0, 0, 0, 0);
          c0 = __builtin_amdgcn_mfma_f32_16x16x32_bf16(al[i], bh[j], c0, 0, 0, 0);
          acc[i][j] = c0;
        }
    } else {
#pragma unroll
      for (int i = 0; i < 4; i++)
#pragma unroll
        for (int j = 0; j < 4; j++)
          acc[i][j] = __builtin_amdgcn_mfma_f32_16x16x32_bf16(ah[i], bh[j], acc[i][j], 0, 0, 0);
    }
  }

  if (z == 2) {
    // V^T store with s-chunk swizzle: within each 64-key block, 8-key chunk
    // c -> c ^ (d&7). uint2 (4 keys, s%8 in {0,4}) stays inside one chunk.
#pragma unroll
    for (int i = 0; i < 4; i++)
#pragma unroll
      for (int j = 0; j < 4; j++) {
        int mg = M0 + mb + i * 16 + quad * 4;
        int ng = N0 + nb + j * 16 + l16;
        int b = mg >> 11, s = mg & 2047;
        int hh = ng >> 6, d = ng & 63;
        int cp = ((s >> 3) & 7) ^ (d & 7);
        int ssw = (s & ~63) | (cp << 3) | (s & 7);
        u16 p0 = bf16_rne(acc[i][j][0]);
        u16 p1 = bf16_rne(acc[i][j][1]);
        u16 p2 = bf16_rne(acc[i][j][2]);
        u16 p3 = bf16_rne(acc[i][j][3]);
        *(uint2*)&dsth[((size_t)(hh * 2 + b) * 64 + d) * 2048 + ssw] =
            make_uint2((u32)p0 | ((u32)p1 << 16), (u32)p2 | ((u32)p3 << 16));
      }
  } else {
    float qscale = (z == 0) ? 0.125f : 1.0f;  // fold 1/sqrt(dh) into Q (exact pow2)
#pragma unroll
    for (int i = 0; i < 4; i++)
#pragma unroll
      for (int j = 0; j < 4; j++)
#pragma unroll
        for (int r = 0; r < 4; r++) {
          int mg = M0 + mb + i * 16 + quad * 4 + r;
          int ng = N0 + nb + j * 16 + l16;
          int b = mg >> 11, s = mg & 2047;
          int hh = ng >> 6, d = ng & 63;
          int d2 = d;
          if (z == 1) d2 = ((((d >> 3) ^ (s & 7)) & 7) << 3) | (d & 7);  // K swizzle
          size_t idx = ((size_t)(hh * 2 + b) * 2048 + s) * 64 + d2;
          float y = acc[i][j][r] * qscale;
          u16 h = bf16_rne(y);
          dsth[idx] = h;
          dstl[idx] = bf16_rne(y - bf16_f(h));
        }
  }
}

// ---------------- flash attention: 32x32 MFMA, S^T in-register, dbuf ----------------
// grid 512 (= 2 blocks/CU), 4 waves/block, 32 queries/wave (BQ=128).
// S^T = K·Q^T: C-layout col = query = lane&31 -> softmax stats are per-lane
// scalars; P^T B-operand assembled via 8 shfl_xor(32)/iter (no LDS P).
// K/V tiles: 128B rows, chunk ^= row&7 (baked into global layout) -> each
// 8-lane phase of a b128 read hits 8 distinct bank groups (conflict-free).
__global__ __launch_bounds__(256, 2) void k_attn(u16* __restrict__ ws,
                                                 float* __restrict__ out) {
  const u16* Qh = ws + Q_HI_E;
  const u16* Ql = ws + Q_LO_E;
  const u16* Kh = ws + K_HI_E;
  const u16* Kl = ws + K_LO_E;
  const u16* Vt = ws + V_HI_E;

  __shared__ u16 sKh[2][64][64], sKl[2][64][64], sVt[2][64][64];  // 48 KB

  int id = blockIdx.x;
  int hb = id & 31, qb = id >> 5;  // id&7 = XCD: all 16 q-blocks of hb share an XCD
  int tid = threadIdx.x, w = tid >> 6, lane = tid & 63;
  int l31 = lane & 31, h = lane >> 5;
  size_t base = (size_t)hb * (2048 * 64);
  int qw0 = qb * 128 + w * 32;

  int srow = lane >> 3, sch = lane & 7;  // staging: 8 rows x 128B per wave-load

  auto stage = [&](int buf, int kt) {
#pragma unroll
    for (int b2 = 0; b2 < 2; b2++) {
      int rr = w * 16 + b2 * 8;
      size_t kg = base + (size_t)(kt + rr + srow) * 64 + sch * 8;
      gload16(Kh + kg, &sKh[buf][rr][0]);
      gload16(Kl + kg, &sKl[buf][rr][0]);
      size_t vg = base + (size_t)(rr + srow) * 2048 + kt + sch * 8;
      gload16(Vt + vg, &sVt[buf][rr][0]);
    }
  };

  stage(0, 0);

  // Q B-operand frags (n = query = l31, k-step ks: d = ks*16 + h*8 + j), linear layout
  bf16x8 qh[4], ql[4];
#pragma unroll
  for (int ks = 0; ks < 4; ks++) {
    size_t off = base + (size_t)(qw0 + l31) * 64 + ks * 16 + h * 8;
    qh[ks] = *(const bf16x8*)(Qh + off);
    ql[ks] = *(const bf16x8*)(Ql + off);
  }

  f32x16 o[2];
#pragma unroll
  for (int i = 0; i < 16; i++) { o[0][i] = 0.f; o[1][i] = 0.f; }
  float mr = -1e30f, lr = 0.f;

  // A-operand read from a swizzled tile: row = mt*32 + l31, chunk = (ks*2+h)^(row&7)
  auto rdA = [&](const u16 t[64][64], int mt, int ks) -> bf16x8 {
    int ch = ((ks * 2 + h) ^ (l31 & 7)) * 8;
    return *(const bf16x8*)&t[mt * 32 + l31][ch];
  };

  for (int it = 0; it < 32; it++) {
    __syncthreads();  // vmcnt(0) drain here: waits DMA issued BEFORE prev compute
    if (it + 1 < 32) stage((it + 1) & 1, (it + 1) * 64);
    int buf = it & 1;

    // S^T = K·Q^T (compensated): lane holds query l31, 32 of 64 keys (its h-half)
    f32x16 sc[2];
#pragma unroll
    for (int i = 0; i < 16; i++) { sc[0][i] = 0.f; sc[1][i] = 0.f; }
#pragma unroll
    for (int ks = 0; ks < 4; ks++)
#pragma unroll
      for (int mt = 0; mt < 2; mt++) {
        bf16x8 kh = rdA(sKh[buf], mt, ks);
        bf16x8 kl = rdA(sKl[buf], mt, ks);
        sc[mt] = __builtin_amdgcn_mfma_f32_32x32x16_bf16(kh, qh[ks], sc[mt], 0, 0, 0);
        sc[mt] = __builtin_amdgcn_mfma_f32_32x32x16_bf16(kh, ql[ks], sc[mt], 0, 0, 0);
        sc[mt] = __builtin_amdgcn_mfma_f32_32x32x16_bf16(kl, qh[ks], sc[mt], 0, 0, 0);
      }

    // online softmax: per-lane scalar stats, 1 shfl for max + 1 for sum
    float mx = sc[0][0];
#pragma unroll
    for (int i = 0; i < 16; i++) {
      mx = fmaxf(mx, sc[0][i]);
      mx = fmaxf(mx, sc[1][i]);
    }
    mx = fmaxf(mx, __shfl_xor(mx, 32));
    float mnew = fmaxf(mr, mx);
    float alpha = __expf(mr - mnew);
    mr = mnew;
    float rs = 0.f;
    u32 pk[2][8];
#pragma unroll
    for (int t = 0; t < 2; t++)
#pragma unroll
      for (int i = 0; i < 8; i++) {
        float p0 = __expf(sc[t][2 * i] - mnew);
        float p1 = __expf(sc[t][2 * i + 1] - mnew);
        rs += p0 + p1;
        u32 a = __float_as_uint(p0) + 0x8000u;
        u32 b = __float_as_uint(p1) + 0x8000u;
        pk[t][i] = __builtin_amdgcn_perm(b, a, 0x07060302u);  // [hi16(a)|hi16(b)]
      }
    rs += __shfl_xor(rs, 32);
    lr = lr * alpha + rs;
#pragma unroll
    for (int i = 0; i < 16; i++) {
      o[0][i] *= alpha;
      o[1][i] *= alpha;
    }

    // O^T += V^T · P^T : B-frag (k=key, n=query) assembled from S^T regs via xor-32
#pragma unroll
    for (int ks = 0; ks < 4; ks++) {
      int t = ks >> 1, c = ks & 1;
      u32 b0 = pk[t][c * 4 + 0], b1 = pk[t][c * 4 + 1];
      u32 b2 = pk[t][c * 4 + 2], b3 = pk[t][c * 4 + 3];
      u32 rA = (u32)__shfl_xor((int)(h ? b0 : b2), 32);
      u32 rB = (u32)__shfl_xor((int)(h ? b1 : b3), 32);
      uint4 fb = h ? make_uint4(rA, rB, b2, b3) : make_uint4(b0, b1, rA, rB);
      bf16x8 pfrag = *(bf16x8*)&fb;
#pragma unroll
      for (int mt = 0; mt < 2; mt++) {
        bf16x8 vb = rdA(sVt[buf], mt, ks);
        o[mt] = __builtin_amdgcn_mfma_f32_32x32x16_bf16(vb, pfrag, o[mt], 0, 0, 0);
      }
    }
  }

  // epilogue: O^T C-layout col = query (per-lane lr), rows = d
  float inv = 1.f / lr;
  size_t grow = (size_t)hb * 2048 + qw0 + l31;
#pragma unroll
  for (int mt = 0; mt < 2; mt++)
#pragma unroll
    for (int g2 = 0; g2 < 4; g2++) {
      int d0 = mt * 32 + g2 * 8 + 4 * h;
      float4 v = make_float4(o[mt][g2 * 4 + 0] * inv, o[mt][g2 * 4 + 1] * inv,
                             o[mt][g2 * 4 + 2] * inv, o[mt][g2 * 4 + 3] * inv);
      *(float4*)(out + grow * 64 + d0) = v;
    }
}

extern "C" void kernel_launch(void* const* d_in, const int* in_sizes, int n_in,
                              void* d_out, int out_size, void* d_ws, size_t ws_size,
                              hipStream_t stream) {
  const float* X = (const float*)d_in[0];
  const float* Wq = (const float*)d_in[1];
  const float* Wk = (const float*)d_in[2];
  const float* Wv = (const float*)d_in[3];
  u16* ws = (u16*)d_ws;
  float* out = (float*)d_out;

  k_xsplit<<<dim3(2048), dim3(256), 0, stream>>>(X, ws);
  k_wsplit<<<dim3(32, 32, 3), dim3(256), 0, stream>>>(Wq, Wk, Wv, ws);
  k_proj<<<dim3(8, 32, 3), dim3(256), 0, stream>>>(ws);
  k_attn<<<dim3(512), dim3(256), 0, stream>>>(ws, out);
}